// Round 3
// baseline (935.677 us; speedup 1.0000x reference)
//
#include <hip/hip_runtime.h>
#include <stdint.h>
#include <math.h>

// ---------------------------------------------------------------------------
// FasterRCNN head on MI355X.
// Cost model: W6 (411MB fp32) + W7 (67MB) streaming dominates -> HBM-bound,
// floor ~76us. fp32 matmul on VALU would be ~250us (no fp32 MFMA on CDNA4),
// so we use bf16 split-precision (a = hi + lo) with 3 MFMA passes:
//   C ~= Ahi*Bhi + Ahi*Blo + Alo*Bhi   (rel err ~2^-17/term, fp32-comparable)
// Per-K-step budget (per CU): HBM 32KB W ~3200 cyc >> MFMA ~500 > LDS ~700
// -> HBM-bound with >3x compute slack; W/partials nontemporal to protect the
// per-XCD A-slab in L2 (split-K slice ks sits in bid low bits -> ks%8 -> XCD).
// ---------------------------------------------------------------------------

typedef short short8 __attribute__((ext_vector_type(8)));
typedef float f32x4 __attribute__((ext_vector_type(4)));

// pack fp32 -> (bf16_lo << 16) | bf16_hi  (both RNE)
__device__ __forceinline__ uint32_t pack_hilo(float x) {
  uint32_t xb = __float_as_uint(x);
  uint32_t hi = (xb + 0x7fffu + ((xb >> 16) & 1u)) >> 16;
  float hf = __uint_as_float(hi << 16);
  float d = x - hf;                       // exact
  uint32_t db = __float_as_uint(d);
  uint32_t lo = (db + 0x7fffu + ((db >> 16) & 1u)) >> 16;
  return (lo << 16) | (hi & 0xffffu);
}

__device__ __forceinline__ short8 mk8(uint32_t a, uint32_t b, uint32_t c, uint32_t d) {
  union { uint32_t u[4]; short8 s; } x;
  x.u[0] = a; x.u[1] = b; x.u[2] = c; x.u[3] = d;
  return x.s;
}

// ---------------------------------------------------------------------------
// 1) transpose features [512][1024] -> feats_t [1024][512]  (coalesced pool)
// ---------------------------------------------------------------------------
__global__ void transpose_k(const float* __restrict__ in, float* __restrict__ out) {
  __shared__ float sm[64][65];
  int bc = blockIdx.x & 7;        // 8 c-tiles
  int bp = blockIdx.x >> 3;       // 16 p-tiles
  int c0 = bc * 64, p0 = bp * 64;
  int tx = threadIdx.x & 63, ty = threadIdx.x >> 6;   // ty 0..3
  for (int r = ty; r < 64; r += 4)
    sm[r][tx] = in[(size_t)(c0 + r) * 1024 + p0 + tx];
  __syncthreads();
  for (int r = ty; r < 64; r += 4)
    out[(size_t)(p0 + r) * 512 + c0 + tx] = sm[tx][r];
}

// ---------------------------------------------------------------------------
// 2) ROI adaptive max pool (reference-exact int arithmetic), emit packed hi/lo
//    Apk [128 rois][25088 = c*49 + ph*7 + pw]
// ---------------------------------------------------------------------------
__global__ void pool_k(const float* __restrict__ feats_t, const float* __restrict__ rois,
                       uint32_t* __restrict__ Apk) {
  int n = blockIdx.x >> 1, half = blockIdx.x & 1;
  int t = threadIdx.x;
  int c = half * 256 + t;
  __shared__ uint32_t sm[256 * 49];

  float r1 = rois[n * 5 + 1], r2 = rois[n * 5 + 2];
  float r3 = rois[n * 5 + 3], r4 = rois[n * 5 + 4];
  int x1 = (int)floorf(r1 * 0.0625f);
  int y1 = (int)floorf(r2 * 0.0625f);
  int x2 = (int)floorf(r3 * 0.0625f);
  int y2 = (int)floorf(r4 * 0.0625f);
  int h = y2 - y1 + 1, w = x2 - x1 + 1;

  for (int cell = 0; cell < 49; ++cell) {
    int i = cell / 7, j = cell % 7;
    int rs = y1 + (i * h) / 7;
    int re = y1 + ((i + 1) * h + 6) / 7;  re = min(re, rs + 5);   // MBr=ceil(32/7)=5
    int cs = x1 + (j * w) / 7;
    int ce = x1 + ((j + 1) * w + 6) / 7;  ce = min(ce, cs + 5);
    float m = -INFINITY;
    for (int r = rs; r < re; ++r)
      for (int cc = cs; cc < ce; ++cc)
        m = fmaxf(m, feats_t[(size_t)(r * 32 + cc) * 512 + c]);
    sm[t * 49 + cell] = pack_hilo(m);
  }
  __syncthreads();
  uint32_t* dst = Apk + (size_t)n * 25088 + (size_t)half * 12544;
  for (int i = t; i < 256 * 49; i += 256) dst[i] = sm[i];
}

// ---------------------------------------------------------------------------
// 3) split-K GEMM: partials[ks][128][4096] = Apk(128 x Ktot) * W(Ktot x 4096)
//    grid = 32 n-blocks * KS k-slices; 256 thr (4 waves); BK=32.
//    LDS rows padded to 36 u32 (144B, <=2-way bank alias = free per m136).
//    W loads nontemporal (stream-once).
// ---------------------------------------------------------------------------
__global__ __launch_bounds__(256, 2)
void gemm_splitk(const uint32_t* __restrict__ Apk, const float* __restrict__ W,
                 float* __restrict__ partials, int Ktot, int ksteps, int ksh) {
  const int t = threadIdx.x;
  const int wvid = t >> 6, lane = t & 63;
  const int bid = blockIdx.x;
  const int nb = bid >> ksh;
  const int ks = bid & ((1 << ksh) - 1);
  const int n0 = nb << 7;
  const int kbase = ks * (ksteps << 5);

  __shared__ uint32_t lsA[128 * 36];
  __shared__ uint32_t lsB[128 * 36];

  // W staging: thread -> (col nloc, k-half); 16 coalesced dword loads/step
  const int nloc = t & 127, khalf = t >> 7;
  const float* wg = W + (size_t)(kbase + khalf * 16) * 4096 + n0 + nloc;

  // A staging: per wave, rows wv*32 + j*8 + (lane>>3), 16B chunk (lane&7)
  const int arow_in = (lane >> 3);
  const int achk = lane & 7;
  const uint32_t* ag = Apk + (size_t)(wvid * 32 + arow_in) * Ktot + kbase + achk * 4;

  f32x4 acc[2][8];
#pragma unroll
  for (int i = 0; i < 2; i++)
#pragma unroll
    for (int j = 0; j < 8; j++) acc[i][j] = f32x4{0.f, 0.f, 0.f, 0.f};

  float wc0[16], wc1[16];
  uint4 ac0[4], ac1[4];

  // prologue: load step 0 (W nontemporal: stream-once, keep A-slab in L2)
#pragma unroll
  for (int i = 0; i < 16; i++) wc0[i] = __builtin_nontemporal_load(wg + (size_t)i * 4096);
#pragma unroll
  for (int j = 0; j < 4; j++) ac0[j] = *(const uint4*)(ag + (size_t)j * 8 * Ktot);

  const int lr = lane & 15, kk = lane >> 4;

  auto step = [&](int s, float (&wc)[16], float (&wn)[16], uint4 (&ac)[4], uint4 (&an)[4]) {
    // convert W fp32 -> packed hi/lo
    uint32_t pk[16];
#pragma unroll
    for (int i = 0; i < 16; i++) pk[i] = pack_hilo(wc[i]);

    __syncthreads();   // all waves done reading previous tile
    // stage B (transposed: [n][k]) and A ([m][k])
#pragma unroll
    for (int i = 0; i < 4; i++)
      *(uint4*)&lsB[nloc * 36 + khalf * 16 + i * 4] =
          make_uint4(pk[i * 4], pk[i * 4 + 1], pk[i * 4 + 2], pk[i * 4 + 3]);
#pragma unroll
    for (int j = 0; j < 4; j++)
      *(uint4*)&lsA[(wvid * 32 + j * 8 + arow_in) * 36 + achk * 4] = ac[j];
    __syncthreads();   // tile visible

    // issue next-step global loads; they fly under the MFMA phase
    if (s + 1 < ksteps) {
      const float* wgs = wg + (size_t)(s + 1) * 32 * 4096;
#pragma unroll
      for (int i = 0; i < 16; i++) wn[i] = __builtin_nontemporal_load(wgs + (size_t)i * 4096);
      const uint32_t* ags = ag + (size_t)(s + 1) * 32;
#pragma unroll
      for (int j = 0; j < 4; j++) an[j] = *(const uint4*)(ags + (size_t)j * 8 * Ktot);
    }

    // A fragments (2 m-frags of 16 rows): lane&15 = row, lane>>4 = k-group
    short8 ahi[2], alo[2];
#pragma unroll
    for (int fm = 0; fm < 2; fm++) {
      int rb = (wvid * 32 + fm * 16 + lr) * 36 + kk * 8;
      uint4 q0 = *(const uint4*)&lsA[rb];
      uint4 q1 = *(const uint4*)&lsA[rb + 4];
      ahi[fm] = mk8(__builtin_amdgcn_perm(q0.y, q0.x, 0x05040100u),
                    __builtin_amdgcn_perm(q0.w, q0.z, 0x05040100u),
                    __builtin_amdgcn_perm(q1.y, q1.x, 0x05040100u),
                    __builtin_amdgcn_perm(q1.w, q1.z, 0x05040100u));
      alo[fm] = mk8(__builtin_amdgcn_perm(q0.y, q0.x, 0x07060302u),
                    __builtin_amdgcn_perm(q0.w, q0.z, 0x07060302u),
                    __builtin_amdgcn_perm(q1.y, q1.x, 0x07060302u),
                    __builtin_amdgcn_perm(q1.w, q1.z, 0x07060302u));
    }
    // B fragments (8 n-frags), 3-pass MFMA
#pragma unroll
    for (int fn = 0; fn < 8; fn++) {
      int rb = (fn * 16 + lr) * 36 + kk * 8;
      uint4 q0 = *(const uint4*)&lsB[rb];
      uint4 q1 = *(const uint4*)&lsB[rb + 4];
      short8 bhi = mk8(__builtin_amdgcn_perm(q0.y, q0.x, 0x05040100u),
                       __builtin_amdgcn_perm(q0.w, q0.z, 0x05040100u),
                       __builtin_amdgcn_perm(q1.y, q1.x, 0x05040100u),
                       __builtin_amdgcn_perm(q1.w, q1.z, 0x05040100u));
      short8 blo = mk8(__builtin_amdgcn_perm(q0.y, q0.x, 0x07060302u),
                       __builtin_amdgcn_perm(q0.w, q0.z, 0x07060302u),
                       __builtin_amdgcn_perm(q1.y, q1.x, 0x07060302u),
                       __builtin_amdgcn_perm(q1.w, q1.z, 0x07060302u));
#pragma unroll
      for (int fm = 0; fm < 2; fm++) {
        acc[fm][fn] = __builtin_amdgcn_mfma_f32_16x16x32_bf16(ahi[fm], bhi, acc[fm][fn], 0, 0, 0);
        acc[fm][fn] = __builtin_amdgcn_mfma_f32_16x16x32_bf16(ahi[fm], blo, acc[fm][fn], 0, 0, 0);
        acc[fm][fn] = __builtin_amdgcn_mfma_f32_16x16x32_bf16(alo[fm], bhi, acc[fm][fn], 0, 0, 0);
      }
    }
  };

  for (int s = 0; s < ksteps; s += 2) {
    step(s, wc0, wc1, ac0, ac1);
    if (s + 1 < ksteps) step(s + 1, wc1, wc0, ac1, ac0);
  }

  // epilogue: D layout col=lane&15, row=(lane>>4)*4+reg  [m89-verified]
  float* pout = partials + (size_t)ks * 524288;
  const int rq = lane >> 4;
#pragma unroll
  for (int fm = 0; fm < 2; fm++)
#pragma unroll
    for (int fn = 0; fn < 8; fn++)
#pragma unroll
      for (int r = 0; r < 4; r++) {
        int row = wvid * 32 + fm * 16 + rq * 4 + r;
        int col = n0 + fn * 16 + lr;
        __builtin_nontemporal_store(acc[fm][fn][r], pout + (size_t)row * 4096 + col);
      }
}

// ---------------------------------------------------------------------------
// 4) reduce K-slices + bias + ReLU -> packed hi/lo (next GEMM) or fp32
//    float4-vectorized; 512 blocks x 256 thr cover 128x4096.
// ---------------------------------------------------------------------------
__global__ void reduce_k(const float* __restrict__ partials, const float* __restrict__ bias,
                         uint32_t* __restrict__ pkout, float* __restrict__ fout, int KS) {
  int base = (blockIdx.x * 256 + threadIdx.x) * 4;   // 524288 total elems
  float4 s = make_float4(0.f, 0.f, 0.f, 0.f);
  for (int k = 0; k < KS; k++) {
    const float4 p = *(const float4*)(partials + (size_t)k * 524288 + base);
    s.x += p.x; s.y += p.y; s.z += p.z; s.w += p.w;
  }
  const float4 bv = *(const float4*)(bias + (base & 4095));
  s.x = fmaxf(s.x + bv.x, 0.f); s.y = fmaxf(s.y + bv.y, 0.f);
  s.z = fmaxf(s.z + bv.z, 0.f); s.w = fmaxf(s.w + bv.w, 0.f);
  if (pkout) {
    uint4 o = make_uint4(pack_hilo(s.x), pack_hilo(s.y), pack_hilo(s.z), pack_hilo(s.w));
    *(uint4*)(pkout + base) = o;
  } else {
    *(float4*)(fout + base) = s;
  }
}

// ---------------------------------------------------------------------------
// 5) heads: logits = x2 @ [Ws|Wb] + [bs|bb]; softmax over first 21; concat
//    512 thr: j = t&127 (output col), kq = t>>7 (K quarter of 1024).
// ---------------------------------------------------------------------------
__global__ void heads_k(const float* __restrict__ x2, const float* __restrict__ Ws,
                        const float* __restrict__ bs, const float* __restrict__ Wb,
                        const float* __restrict__ bb, float* __restrict__ out) {
  int n = blockIdx.x, t = threadIdx.x;
  int j = t & 127, kq = t >> 7;    // kq 0..3
  float a0 = 0.f, a1 = 0.f, a2 = 0.f, a3 = 0.f;
  if (j < 105) {
    const float* xp = x2 + (size_t)n * 4096 + kq * 1024;
    const float* wq;
    int stride;
    if (j < 21) { wq = Ws + (size_t)kq * 1024 * 21 + j; stride = 21; }
    else        { wq = Wb + (size_t)kq * 1024 * 84 + (j - 21); stride = 84; }
    for (int k = 0; k < 1024; k += 4) {
      const float4 xv = *(const float4*)(xp + k);
      a0 += xv.x * wq[(size_t)k * stride];
      a1 += xv.y * wq[(size_t)(k + 1) * stride];
      a2 += xv.z * wq[(size_t)(k + 2) * stride];
      a3 += xv.w * wq[(size_t)(k + 3) * stride];
    }
  }
  __shared__ float sacc[512];
  __shared__ float slog[105];
  sacc[t] = (a0 + a1) + (a2 + a3);
  __syncthreads();
  if (t < 105)
    slog[t] = (sacc[t] + sacc[t + 128]) + (sacc[t + 256] + sacc[t + 384]) +
              (t < 21 ? bs[t] : bb[t - 21]);
  __syncthreads();
  if (t < 105) {
    float v = slog[t];
    if (t < 21) {
      float m = slog[0];
      for (int q = 1; q < 21; q++) m = fmaxf(m, slog[q]);
      float ssum = 0.f;
      for (int q = 0; q < 21; q++) ssum += expf(slog[q] - m);
      v = expf(v - m) / ssum;
    }
    out[(size_t)n * 105 + t] = v;
  }
}

// ---------------------------------------------------------------------------
extern "C" void kernel_launch(void* const* d_in, const int* in_sizes, int n_in,
                              void* d_out, int out_size, void* d_ws, size_t ws_size,
                              hipStream_t stream) {
  const float* feats = (const float*)d_in[0];
  const float* rois  = (const float*)d_in[1];
  const float* W6 = (const float*)d_in[2];
  const float* b6 = (const float*)d_in[3];
  const float* W7 = (const float*)d_in[4];
  const float* b7 = (const float*)d_in[5];
  const float* Wsp = (const float*)d_in[6];
  const float* bsp = (const float*)d_in[7];
  const float* Wbp = (const float*)d_in[8];
  const float* bbp = (const float*)d_in[9];
  float* out = (float*)d_out;

  char* ws = (char*)d_ws;
  size_t o = 0;
  float*    feats_t = (float*)(ws + o);    o += (size_t)512 * 1024 * 4;   // 2MB
  uint32_t* Apk     = (uint32_t*)(ws + o); o += (size_t)128 * 25088 * 4;  // 12.85MB
  uint32_t* A2pk    = (uint32_t*)(ws + o); o += (size_t)128 * 4096 * 4;   // 2MB
  float*    x2      = (float*)(ws + o);    o += (size_t)128 * 4096 * 4;   // 2MB
  size_t fixed = o;
  int KS = 16;                              // k-slices for FC6; shrink if ws small
  while (KS > 1 && fixed + (size_t)KS * 524288 * 4 > ws_size) KS >>= 1;
  float* partials = (float*)(ws + o);
  int ksh = (KS == 16) ? 4 : (KS == 8) ? 3 : (KS == 4) ? 2 : (KS == 2) ? 1 : 0;
  int ksh7 = (ksh > 3) ? 3 : ksh;           // FC7: KS=8 (halve partial traffic)
  int KS7 = 1 << ksh7;

  hipLaunchKernelGGL(transpose_k, dim3(128), dim3(256), 0, stream, feats, feats_t);
  hipLaunchKernelGGL(pool_k, dim3(256), dim3(256), 0, stream, feats_t, rois, Apk);
  hipLaunchKernelGGL(gemm_splitk, dim3(32 << ksh), dim3(256), 0, stream,
                     Apk, W6, partials, 25088, 25088 / (KS * 32), ksh);
  hipLaunchKernelGGL(reduce_k, dim3(512), dim3(256), 0, stream,
                     partials, b6, A2pk, (float*)nullptr, KS);
  hipLaunchKernelGGL(gemm_splitk, dim3(32 << ksh7), dim3(256), 0, stream,
                     A2pk, W7, partials, 4096, 4096 / (KS7 * 32), ksh7);
  hipLaunchKernelGGL(reduce_k, dim3(512), dim3(256), 0, stream,
                     partials, b7, (uint32_t*)nullptr, x2, KS7);
  hipLaunchKernelGGL(heads_k, dim3(128), dim3(512), 0, stream,
                     x2, Wsp, bsp, Wbp, bbp, out);
}

// Round 4
// 932.047 us; speedup vs baseline: 1.0039x; 1.0039x over previous
//
#include <hip/hip_runtime.h>
#include <stdint.h>
#include <math.h>

// ---------------------------------------------------------------------------
// FasterRCNN head on MI355X.
// HBM-bound: W6 411MB + W7 67MB fp32 stream -> floor ~76us @6.3TB/s.
// No fp32 MFMA on CDNA4 -> split-bf16 (x = hi + lo), 3 MFMA passes:
//   C ~= Ahi*Bhi + Ahi*Blo + Alo*Bhi   (rel err ~2^-17, measured absmax 4e-3)
// r4 changes vs r3 (dur_us 936, fills dominated profile):
//  - depth-2 software pipeline: tile s+2 loads issued before tile s MFMA
//    (~1500cy cover vs ~900cy HBM latency; r3 covered only ~650cy)
//  - A pre-split into hi/lo bf16-pair arrays at producer (pool/reduce);
//    W packed into pair format at staging -> consumer v_perm 80->0 per lane.
//  - LDS: 4 regions x 128 rows x pitch 20 u32 (16B-aligned, <=2-way banks).
// ---------------------------------------------------------------------------

typedef short short8 __attribute__((ext_vector_type(8)));
typedef float f32x4 __attribute__((ext_vector_type(4)));

// pack fp32 -> (bf16_lo << 16) | bf16_hi  (both RNE)
__device__ __forceinline__ uint32_t pack_hilo(float x) {
  uint32_t xb = __float_as_uint(x);
  uint32_t hi = (xb + 0x7fffu + ((xb >> 16) & 1u)) >> 16;
  float hf = __uint_as_float(hi << 16);
  float d = x - hf;                       // exact
  uint32_t db = __float_as_uint(d);
  uint32_t lo = (db + 0x7fffu + ((db >> 16) & 1u)) >> 16;
  return (lo << 16) | (hi & 0xffffu);
}

// pair of fp32 -> hi-word (hi1<<16|hi0) and lo-word (lo1<<16|lo0), RNE
__device__ __forceinline__ void pack_pair(float x0, float x1,
                                          uint32_t& hw, uint32_t& lw) {
  uint32_t u0 = __float_as_uint(x0), u1 = __float_as_uint(x1);
  uint32_t r0 = (u0 + 0x7fffu + ((u0 >> 16) & 1u)) & 0xffff0000u;
  uint32_t r1 = (u1 + 0x7fffu + ((u1 >> 16) & 1u)) & 0xffff0000u;
  hw = r1 | (r0 >> 16);
  float d0 = x0 - __uint_as_float(r0);
  float d1 = x1 - __uint_as_float(r1);
  uint32_t v0 = __float_as_uint(d0), v1 = __float_as_uint(d1);
  uint32_t s0 = (v0 + 0x7fffu + ((v0 >> 16) & 1u)) & 0xffff0000u;
  uint32_t s1 = (v1 + 0x7fffu + ((v1 >> 16) & 1u)) & 0xffff0000u;
  lw = s1 | (s0 >> 16);
}

__device__ __forceinline__ short8 lds_frag(const uint32_t* p) {
  union { uint4 q; short8 s; } x;
  x.q = *(const uint4*)p;
  return x.s;
}

// ---------------------------------------------------------------------------
// 1) transpose features [512][1024] -> feats_t [1024][512]
// ---------------------------------------------------------------------------
__global__ void transpose_k(const float* __restrict__ in, float* __restrict__ out) {
  __shared__ float sm[64][65];
  int bc = blockIdx.x & 7;
  int bp = blockIdx.x >> 3;
  int c0 = bc * 64, p0 = bp * 64;
  int tx = threadIdx.x & 63, ty = threadIdx.x >> 6;
  for (int r = ty; r < 64; r += 4)
    sm[r][tx] = in[(size_t)(c0 + r) * 1024 + p0 + tx];
  __syncthreads();
  for (int r = ty; r < 64; r += 4)
    out[(size_t)(p0 + r) * 512 + c0 + tx] = sm[tx][r];
}

// ---------------------------------------------------------------------------
// 2) ROI adaptive max pool -> split hi/lo bf16-pair arrays
//    Ahi/Alo [128 rois][12544 = 25088/2 k-pairs], k = c*49 + cell
// ---------------------------------------------------------------------------
__global__ void pool_k(const float* __restrict__ feats_t, const float* __restrict__ rois,
                       uint32_t* __restrict__ Ahi, uint32_t* __restrict__ Alo) {
  int n = blockIdx.x >> 1, half = blockIdx.x & 1;
  int t = threadIdx.x;
  int c = half * 256 + t;
  __shared__ uint32_t sm[256 * 49];

  float r1 = rois[n * 5 + 1], r2 = rois[n * 5 + 2];
  float r3 = rois[n * 5 + 3], r4 = rois[n * 5 + 4];
  int x1 = (int)floorf(r1 * 0.0625f);
  int y1 = (int)floorf(r2 * 0.0625f);
  int x2 = (int)floorf(r3 * 0.0625f);
  int y2 = (int)floorf(r4 * 0.0625f);
  int h = y2 - y1 + 1, w = x2 - x1 + 1;

  for (int cell = 0; cell < 49; ++cell) {
    int i = cell / 7, j = cell % 7;
    int rs = y1 + (i * h) / 7;
    int re = y1 + ((i + 1) * h + 6) / 7;  re = min(re, rs + 5);
    int cs = x1 + (j * w) / 7;
    int ce = x1 + ((j + 1) * w + 6) / 7;  ce = min(ce, cs + 5);
    float m = -INFINITY;
    for (int r = rs; r < re; ++r)
      for (int cc = cs; cc < ce; ++cc)
        m = fmaxf(m, feats_t[(size_t)(r * 32 + cc) * 512 + c]);
    sm[t * 49 + cell] = pack_hilo(m);
  }
  __syncthreads();
  uint32_t* dh = Ahi + (size_t)n * 12544 + (size_t)half * 6272;
  uint32_t* dl = Alo + (size_t)n * 12544 + (size_t)half * 6272;
  for (int i = t; i < 6272; i += 256) {
    uint32_t w0 = sm[2 * i], w1 = sm[2 * i + 1];   // (lo<<16|hi) each
    dh[i] = __builtin_amdgcn_perm(w1, w0, 0x05040100u);  // hi1<<16|hi0
    dl[i] = __builtin_amdgcn_perm(w1, w0, 0x07060302u);  // lo1<<16|lo0
  }
}

// ---------------------------------------------------------------------------
// 3) split-K GEMM: partials[ks][128][4096] = A(128 x K) * W(K x 4096)
//    A pre-split (Ahi/Alo pair-format, row stride Khalf u32).
//    grid = 32 n-blocks * KS k-slices; 256 thr; BK=32; depth-2 pipeline.
// ---------------------------------------------------------------------------
__global__ __launch_bounds__(256, 2)
void gemm_splitk(const uint32_t* __restrict__ Ahi, const uint32_t* __restrict__ Alo,
                 const float* __restrict__ W, float* __restrict__ partials,
                 int Khalf, int ksteps, int ksh) {
  const int t = threadIdx.x;
  const int wvid = t >> 6, lane = t & 63;
  const int nb = blockIdx.x >> ksh;
  const int ks = blockIdx.x & ((1 << ksh) - 1);
  const int n0 = nb << 7;
  const int kbase2 = ks * (ksteps << 4);           // u32-pair offset

  __shared__ uint32_t lds[4][128 * 20];            // Ahi, Alo, Bhi, Blo; pitch 20

  // W staging: thread -> (col nloc, k-half of 16); 16 coalesced NT dwords/step
  const int nloc = t & 127, khalf = t >> 7;
  const float* wg = W + ((size_t)kbase2 * 2 + khalf * 16) * 4096 + n0 + nloc;

  // A staging: row = wv*32 + (lane>>1); lane&1 selects u32 8..15 vs 0..7
  const int arow = wvid * 32 + (lane >> 1);
  const int aco = (lane & 1) * 8;                  // u32 offset within row-step
  const uint32_t* agh = Ahi + (size_t)arow * Khalf + kbase2 + aco;
  const uint32_t* agl = Alo + (size_t)arow * Khalf + kbase2 + aco;

  f32x4 acc[2][8];
#pragma unroll
  for (int i = 0; i < 2; i++)
#pragma unroll
    for (int j = 0; j < 8; j++) acc[i][j] = f32x4{0.f, 0.f, 0.f, 0.f};

  float wcA[16], wcB[16];
  uint4 aA[4], aB[4];

  auto issue = [&](float (&wc)[16], uint4 (&av)[4], int s) {
    const float* wp = wg + (size_t)s * 32 * 4096;
#pragma unroll
    for (int i = 0; i < 16; i++) wc[i] = __builtin_nontemporal_load(wp + (size_t)i * 4096);
    const uint32_t* ph = agh + (size_t)s * 16;
    const uint32_t* pl = agl + (size_t)s * 16;
    av[0] = *(const uint4*)(ph);
    av[1] = *(const uint4*)(ph + 4);
    av[2] = *(const uint4*)(pl);
    av[3] = *(const uint4*)(pl + 4);
  };

  // pack W regs and store tile to LDS (barrier before+after handled by caller)
  auto pack_w = [&](float (&wc)[16], uint32_t (&hw)[8], uint32_t (&lw)[8]) {
#pragma unroll
    for (int j = 0; j < 8; j++) pack_pair(wc[2 * j], wc[2 * j + 1], hw[j], lw[j]);
  };
  auto store_tile = [&](uint32_t (&hw)[8], uint32_t (&lw)[8], uint4 (&av)[4]) {
    // B: row nloc, words khalf*8 + 0..7 in Bhi/Blo
    *(uint4*)&lds[2][nloc * 20 + khalf * 8]     = make_uint4(hw[0], hw[1], hw[2], hw[3]);
    *(uint4*)&lds[2][nloc * 20 + khalf * 8 + 4] = make_uint4(hw[4], hw[5], hw[6], hw[7]);
    *(uint4*)&lds[3][nloc * 20 + khalf * 8]     = make_uint4(lw[0], lw[1], lw[2], lw[3]);
    *(uint4*)&lds[3][nloc * 20 + khalf * 8 + 4] = make_uint4(lw[4], lw[5], lw[6], lw[7]);
    // A: row arow, u32 aco..aco+7 in Ahi/Alo
    *(uint4*)&lds[0][arow * 20 + aco]     = av[0];
    *(uint4*)&lds[0][arow * 20 + aco + 4] = av[1];
    *(uint4*)&lds[1][arow * 20 + aco]     = av[2];
    *(uint4*)&lds[1][arow * 20 + aco + 4] = av[3];
  };

  const int lr = lane & 15, kk = lane >> 4;

  auto mfma_tile = [&]() {
    short8 ahif[2], alof[2];
#pragma unroll
    for (int fm = 0; fm < 2; fm++) {
      int rb = (wvid * 32 + fm * 16 + lr) * 20 + kk * 4;
      ahif[fm] = lds_frag(&lds[0][rb]);
      alof[fm] = lds_frag(&lds[1][rb]);
    }
#pragma unroll
    for (int fn = 0; fn < 8; fn++) {
      int rb = (fn * 16 + lr) * 20 + kk * 4;
      short8 bhi = lds_frag(&lds[2][rb]);
      short8 blo = lds_frag(&lds[3][rb]);
#pragma unroll
      for (int fm = 0; fm < 2; fm++) {
        acc[fm][fn] = __builtin_amdgcn_mfma_f32_16x16x32_bf16(ahif[fm], bhi, acc[fm][fn], 0, 0, 0);
        acc[fm][fn] = __builtin_amdgcn_mfma_f32_16x16x32_bf16(ahif[fm], blo, acc[fm][fn], 0, 0, 0);
        acc[fm][fn] = __builtin_amdgcn_mfma_f32_16x16x32_bf16(alof[fm], bhi, acc[fm][fn], 0, 0, 0);
      }
    }
  };

  // prologue: tile0 -> LDS; tile1 raw in (wcB,aB)
  issue(wcA, aA, 0);
  if (ksteps > 1) issue(wcB, aB, 1);
  {
    uint32_t hw[8], lw[8];
    pack_w(wcA, hw, lw);
    store_tile(hw, lw, aA);
  }
  __syncthreads();

  for (int s = 0; s < ksteps; s += 2) {
    // tile s; raw s+1 in (wcB,aB); prefetch s+2 -> (wcA,aA)
    if (s + 2 < ksteps) issue(wcA, aA, s + 2);
    mfma_tile();
    if (s + 1 < ksteps) {
      uint32_t hw[8], lw[8];
      pack_w(wcB, hw, lw);
      __syncthreads();                 // all waves done reading tile s
      store_tile(hw, lw, aB);
      __syncthreads();                 // tile s+1 visible
      // tile s+1; raw s+2 in (wcA,aA); prefetch s+3 -> (wcB,aB)
      if (s + 3 < ksteps) issue(wcB, aB, s + 3);
      mfma_tile();
      if (s + 2 < ksteps) {
        uint32_t hw2[8], lw2[8];
        pack_w(wcA, hw2, lw2);
        __syncthreads();
        store_tile(hw2, lw2, aA);
        __syncthreads();
      }
    }
  }

  // epilogue: D layout col=lane&15, row=(lane>>4)*4+reg  [m89-verified]
  float* pout = partials + (size_t)ks * 524288;
  const int rq = lane >> 4;
#pragma unroll
  for (int fm = 0; fm < 2; fm++)
#pragma unroll
    for (int fn = 0; fn < 8; fn++)
#pragma unroll
      for (int r = 0; r < 4; r++) {
        int row = wvid * 32 + fm * 16 + rq * 4 + r;
        int col = n0 + fn * 16 + lr;
        __builtin_nontemporal_store(acc[fm][fn][r], pout + (size_t)row * 4096 + col);
      }
}

// ---------------------------------------------------------------------------
// 4) reduce K-slices + bias + ReLU -> split pair arrays (next GEMM) or fp32
// ---------------------------------------------------------------------------
__global__ void reduce_k(const float* __restrict__ partials, const float* __restrict__ bias,
                         uint32_t* __restrict__ outhi, uint32_t* __restrict__ outlo,
                         float* __restrict__ fout, int KS) {
  int idx = blockIdx.x * 256 + threadIdx.x;
  int base = idx * 4;                               // 524288 total elems
  float4 s = make_float4(0.f, 0.f, 0.f, 0.f);
  for (int k = 0; k < KS; k++) {
    const float4 p = *(const float4*)(partials + (size_t)k * 524288 + base);
    s.x += p.x; s.y += p.y; s.z += p.z; s.w += p.w;
  }
  const float4 bv = *(const float4*)(bias + (base & 4095));
  s.x = fmaxf(s.x + bv.x, 0.f); s.y = fmaxf(s.y + bv.y, 0.f);
  s.z = fmaxf(s.z + bv.z, 0.f); s.w = fmaxf(s.w + bv.w, 0.f);
  if (outhi) {
    uint32_t h0, l0, h1, l1;
    pack_pair(s.x, s.y, h0, l0);
    pack_pair(s.z, s.w, h1, l1);
    *(uint2*)(outhi + idx * 2) = make_uint2(h0, h1);
    *(uint2*)(outlo + idx * 2) = make_uint2(l0, l1);
  } else {
    *(float4*)(fout + base) = s;
  }
}

// ---------------------------------------------------------------------------
// 5) heads: logits = x2 @ [Ws|Wb] + [bs|bb]; softmax over first 21; concat
// ---------------------------------------------------------------------------
__global__ void heads_k(const float* __restrict__ x2, const float* __restrict__ Ws,
                        const float* __restrict__ bs, const float* __restrict__ Wb,
                        const float* __restrict__ bb, float* __restrict__ out) {
  int n = blockIdx.x, t = threadIdx.x;
  int j = t & 127, kq = t >> 7;    // kq 0..3
  float a0 = 0.f, a1 = 0.f, a2 = 0.f, a3 = 0.f;
  if (j < 105) {
    const float* xp = x2 + (size_t)n * 4096 + kq * 1024;
    const float* wq;
    int stride;
    if (j < 21) { wq = Ws + (size_t)kq * 1024 * 21 + j; stride = 21; }
    else        { wq = Wb + (size_t)kq * 1024 * 84 + (j - 21); stride = 84; }
    for (int k = 0; k < 1024; k += 4) {
      const float4 xv = *(const float4*)(xp + k);
      a0 += xv.x * wq[(size_t)k * stride];
      a1 += xv.y * wq[(size_t)(k + 1) * stride];
      a2 += xv.z * wq[(size_t)(k + 2) * stride];
      a3 += xv.w * wq[(size_t)(k + 3) * stride];
    }
  }
  __shared__ float sacc[512];
  __shared__ float slog[105];
  sacc[t] = (a0 + a1) + (a2 + a3);
  __syncthreads();
  if (t < 105)
    slog[t] = (sacc[t] + sacc[t + 128]) + (sacc[t + 256] + sacc[t + 384]) +
              (t < 21 ? bs[t] : bb[t - 21]);
  __syncthreads();
  if (t < 105) {
    float v = slog[t];
    if (t < 21) {
      float m = slog[0];
      for (int q = 1; q < 21; q++) m = fmaxf(m, slog[q]);
      float ssum = 0.f;
      for (int q = 0; q < 21; q++) ssum += expf(slog[q] - m);
      v = expf(v - m) / ssum;
    }
    out[(size_t)n * 105 + t] = v;
  }
}

// ---------------------------------------------------------------------------
extern "C" void kernel_launch(void* const* d_in, const int* in_sizes, int n_in,
                              void* d_out, int out_size, void* d_ws, size_t ws_size,
                              hipStream_t stream) {
  const float* feats = (const float*)d_in[0];
  const float* rois  = (const float*)d_in[1];
  const float* W6 = (const float*)d_in[2];
  const float* b6 = (const float*)d_in[3];
  const float* W7 = (const float*)d_in[4];
  const float* b7 = (const float*)d_in[5];
  const float* Wsp = (const float*)d_in[6];
  const float* bsp = (const float*)d_in[7];
  const float* Wbp = (const float*)d_in[8];
  const float* bbp = (const float*)d_in[9];
  float* out = (float*)d_out;

  char* ws = (char*)d_ws;
  size_t o = 0;
  float*    feats_t = (float*)(ws + o);    o += (size_t)512 * 1024 * 4;     // 2MB
  uint32_t* Ahi     = (uint32_t*)(ws + o); o += (size_t)128 * 12544 * 4;    // 6.4MB
  uint32_t* Alo     = (uint32_t*)(ws + o); o += (size_t)128 * 12544 * 4;    // 6.4MB
  uint32_t* A2hi    = (uint32_t*)(ws + o); o += (size_t)128 * 2048 * 4;     // 1MB
  uint32_t* A2lo    = (uint32_t*)(ws + o); o += (size_t)128 * 2048 * 4;     // 1MB
  float*    x2      = (float*)(ws + o);    o += (size_t)128 * 4096 * 4;     // 2MB
  size_t fixed = o;
  int KS = 16;
  while (KS > 1 && fixed + (size_t)KS * 524288 * 4 > ws_size) KS >>= 1;
  float* partials = (float*)(ws + o);
  int ksh = (KS == 16) ? 4 : (KS == 8) ? 3 : (KS == 4) ? 2 : (KS == 2) ? 1 : 0;
  int ksh7 = (ksh > 3) ? 3 : ksh;           // FC7: KS=8
  int KS7 = 1 << ksh7;

  hipLaunchKernelGGL(transpose_k, dim3(128), dim3(256), 0, stream, feats, feats_t);
  hipLaunchKernelGGL(pool_k, dim3(256), dim3(256), 0, stream, feats_t, rois, Ahi, Alo);
  hipLaunchKernelGGL(gemm_splitk, dim3(32 << ksh), dim3(256), 0, stream,
                     Ahi, Alo, W6, partials, 12544, 25088 / (KS * 32), ksh);
  hipLaunchKernelGGL(reduce_k, dim3(512), dim3(256), 0, stream,
                     partials, b6, A2hi, A2lo, (float*)nullptr, KS);
  hipLaunchKernelGGL(gemm_splitk, dim3(32 << ksh7), dim3(256), 0, stream,
                     A2hi, A2lo, W7, partials, 2048, 4096 / (KS7 * 32), ksh7);
  hipLaunchKernelGGL(reduce_k, dim3(512), dim3(256), 0, stream,
                     partials, b7, (uint32_t*)nullptr, (uint32_t*)nullptr, x2, KS7);
  hipLaunchKernelGGL(heads_k, dim3(128), dim3(512), 0, stream,
                     x2, Wsp, bsp, Wbp, bbp, out);
}

// Round 5
// 899.665 us; speedup vs baseline: 1.0400x; 1.0360x over previous
//
#include <hip/hip_runtime.h>
#include <stdint.h>
#include <math.h>

// ---------------------------------------------------------------------------
// FasterRCNN head on MI355X — r5: BARRIER-FREE, LDS-FREE split-bf16 GEMM.
// Evidence: r3->r4 (removed 80 perms/lane/step, deeper prefetch) moved dur_us
// 936->932 => GEMM insensitive to VALU => barrier-drain-bound (vmcnt(0) before
// every s_barrier drains prefetch; 98 drains per FC6 block) or harness floor.
// Fix: wave-private 32-col strips => W fragments never shared => no LDS, no
// barriers at all. A re-laid out as [kp4][row][4] u32 so A-frags are coalesced
// dwordx4 from the L2-resident slab (per-XCD ~1.6MB, ks%8->XCD).
//   C ~= Ahi*Bhi + Ahi*Blo + Alo*Bhi  (split-bf16, measured absmax 3.9e-3 OK)
// ---------------------------------------------------------------------------

typedef short short8 __attribute__((ext_vector_type(8)));
typedef float f32x4 __attribute__((ext_vector_type(4)));

// pack fp32 -> (bf16_lo << 16) | bf16_hi  (both RNE)
__device__ __forceinline__ uint32_t pack_hilo(float x) {
  uint32_t xb = __float_as_uint(x);
  uint32_t hi = (xb + 0x7fffu + ((xb >> 16) & 1u)) >> 16;
  float hf = __uint_as_float(hi << 16);
  float d = x - hf;                       // exact
  uint32_t db = __float_as_uint(d);
  uint32_t lo = (db + 0x7fffu + ((db >> 16) & 1u)) >> 16;
  return (lo << 16) | (hi & 0xffffu);
}

// pair of fp32 -> hi-word (hi1<<16|hi0) and lo-word (lo1<<16|lo0), RNE
__device__ __forceinline__ void pack_pair(float x0, float x1,
                                          uint32_t& hw, uint32_t& lw) {
  uint32_t u0 = __float_as_uint(x0), u1 = __float_as_uint(x1);
  uint32_t r0 = (u0 + 0x7fffu + ((u0 >> 16) & 1u)) & 0xffff0000u;
  uint32_t r1 = (u1 + 0x7fffu + ((u1 >> 16) & 1u)) & 0xffff0000u;
  hw = r1 | (r0 >> 16);
  float d0 = x0 - __uint_as_float(r0);
  float d1 = x1 - __uint_as_float(r1);
  uint32_t v0 = __float_as_uint(d0), v1 = __float_as_uint(d1);
  uint32_t s0 = (v0 + 0x7fffu + ((v0 >> 16) & 1u)) & 0xffff0000u;
  uint32_t s1 = (v1 + 0x7fffu + ((v1 >> 16) & 1u)) & 0xffff0000u;
  lw = s1 | (s0 >> 16);
}

__device__ __forceinline__ short8 u4_to_s8(uint4 q) {
  union { uint4 q; short8 s; } x;
  x.q = q;
  return x.s;
}
__device__ __forceinline__ short8 mk8(uint32_t a, uint32_t b, uint32_t c, uint32_t d) {
  union { uint32_t u[4]; short8 s; } x;
  x.u[0] = a; x.u[1] = b; x.u[2] = c; x.u[3] = d;
  return x.s;
}

// ---------------------------------------------------------------------------
// 1) transpose features [512][1024] -> feats_t [1024][512]
// ---------------------------------------------------------------------------
__global__ void transpose_k(const float* __restrict__ in, float* __restrict__ out) {
  __shared__ float sm[64][65];
  int bc = blockIdx.x & 7;
  int bp = blockIdx.x >> 3;
  int c0 = bc * 64, p0 = bp * 64;
  int tx = threadIdx.x & 63, ty = threadIdx.x >> 6;
  for (int r = ty; r < 64; r += 4)
    sm[r][tx] = in[(size_t)(c0 + r) * 1024 + p0 + tx];
  __syncthreads();
  for (int r = ty; r < 64; r += 4)
    out[(size_t)(p0 + r) * 512 + c0 + tx] = sm[tx][r];
}

// ---------------------------------------------------------------------------
// 2) ROI adaptive max pool -> AhiT/AloT in [kp4][row=128][kp&3] u32 layout
//    kp = (c*49+cell)/2 pairs; pair word = (bf16 of k-odd)<<16 | (bf16 k-even)
// ---------------------------------------------------------------------------
__global__ void pool_k(const float* __restrict__ feats_t, const float* __restrict__ rois,
                       uint32_t* __restrict__ AhiT, uint32_t* __restrict__ AloT) {
  int n = blockIdx.x >> 1, half = blockIdx.x & 1;
  int t = threadIdx.x;
  int c = half * 256 + t;
  __shared__ uint32_t sm[256 * 49];

  float r1 = rois[n * 5 + 1], r2 = rois[n * 5 + 2];
  float r3 = rois[n * 5 + 3], r4 = rois[n * 5 + 4];
  int x1 = (int)floorf(r1 * 0.0625f);
  int y1 = (int)floorf(r2 * 0.0625f);
  int x2 = (int)floorf(r3 * 0.0625f);
  int y2 = (int)floorf(r4 * 0.0625f);
  int h = y2 - y1 + 1, w = x2 - x1 + 1;

  for (int cell = 0; cell < 49; ++cell) {
    int i = cell / 7, j = cell % 7;
    int rs = y1 + (i * h) / 7;
    int re = y1 + ((i + 1) * h + 6) / 7;  re = min(re, rs + 5);
    int cs = x1 + (j * w) / 7;
    int ce = x1 + ((j + 1) * w + 6) / 7;  ce = min(ce, cs + 5);
    float m = -INFINITY;
    for (int r = rs; r < re; ++r)
      for (int cc = cs; cc < ce; ++cc)
        m = fmaxf(m, feats_t[(size_t)(r * 32 + cc) * 512 + c]);
    sm[t * 49 + cell] = pack_hilo(m);
  }
  __syncthreads();
  for (int i = t; i < 6272; i += 256) {
    uint32_t w0 = sm[2 * i], w1 = sm[2 * i + 1];   // (lo<<16|hi) each
    int kp = half * 6272 + i;
    size_t ad = ((size_t)(kp >> 2) * 128 + n) * 4 + (kp & 3);
    AhiT[ad] = __builtin_amdgcn_perm(w1, w0, 0x05040100u);  // hi1<<16|hi0
    AloT[ad] = __builtin_amdgcn_perm(w1, w0, 0x07060302u);  // lo1<<16|lo0
  }
}

// ---------------------------------------------------------------------------
// 3) split-K GEMM, NO LDS / NO BARRIERS.
//    partials[ks][128][4096] = A(128 x K) * W(K x 4096)
//    Wave wv owns cols nb*128 + wv*32 .. +31 (2 fn frags), all 128 rows (8 fm).
//    W loaded straight into B-frag layout (wave-private), A from [kp4][128][4].
//    grid = 32 n-blocks * KS k-slices, 256 thr, BK=32, W double-buffered.
// ---------------------------------------------------------------------------
__global__ __launch_bounds__(256, 2)
void gemm_nb(const uint32_t* __restrict__ AhiT, const uint32_t* __restrict__ AloT,
             const float* __restrict__ W, float* __restrict__ partials,
             int ksteps, int ksh) {
  const int t = threadIdx.x, wv = t >> 6, lane = t & 63;
  const int lr = lane & 15, kk = lane >> 4;
  const int nb = blockIdx.x >> ksh, ks = blockIdx.x & ((1 << ksh) - 1);
  const int n0 = (nb << 7) + wv * 32;
  const int kp40 = ks * ksteps * 4;            // slice start in kp4 units

  // W: lane needs col n0+fn*16+lr, k = kp40*8 + s*32 + kk*8 + j
  const float* wg = W + ((size_t)kp40 * 8 + kk * 8) * 4096 + n0 + lr;
  // A: lane's kp4 = kp40 + s*4 + kk; u32 addr = (kp4*128 + row)*4 + (0..3)
  const uint32_t* ah = AhiT + ((size_t)(kp40 + kk) * 128 + lr) * 4;
  const uint32_t* al = AloT + ((size_t)(kp40 + kk) * 128 + lr) * 4;

  f32x4 acc[8][2];
#pragma unroll
  for (int i = 0; i < 8; i++)
#pragma unroll
    for (int j = 0; j < 2; j++) acc[i][j] = f32x4{0.f, 0.f, 0.f, 0.f};

  float wA[16], wB[16];

  auto wissue = [&](float (&wc)[16], int s) {
    const float* p = wg + (size_t)s * 32 * 4096;
#pragma unroll
    for (int fn = 0; fn < 2; fn++)
#pragma unroll
      for (int j = 0; j < 8; j++)
        wc[fn * 8 + j] = __builtin_nontemporal_load(p + (size_t)j * 4096 + fn * 16);
  };

  auto do_tile = [&](int s, float (&wc)[16]) {
    // A fragments for this tile (L2-resident slab; coalesced dwordx4)
    uint4 ahv[8], alv[8];
    const uint32_t* pa = ah + (size_t)s * 2048;   // +4 kp4 = 2048 u32 per tile
    const uint32_t* pl = al + (size_t)s * 2048;
#pragma unroll
    for (int fm = 0; fm < 8; fm++) {
      ahv[fm] = *(const uint4*)(pa + fm * 64);    // row fm*16+lr
      alv[fm] = *(const uint4*)(pl + fm * 64);
    }
    // pack W regs -> wave-private B fragments
    uint32_t bh[2][4], bl[2][4];
#pragma unroll
    for (int fn = 0; fn < 2; fn++)
#pragma unroll
      for (int jj = 0; jj < 4; jj++)
        pack_pair(wc[fn * 8 + 2 * jj], wc[fn * 8 + 2 * jj + 1], bh[fn][jj], bl[fn][jj]);
#pragma unroll
    for (int fn = 0; fn < 2; fn++) {
      short8 b_hi = mk8(bh[fn][0], bh[fn][1], bh[fn][2], bh[fn][3]);
      short8 b_lo = mk8(bl[fn][0], bl[fn][1], bl[fn][2], bl[fn][3]);
#pragma unroll
      for (int fm = 0; fm < 8; fm++) {
        short8 a_hi = u4_to_s8(ahv[fm]);
        short8 a_lo = u4_to_s8(alv[fm]);
        acc[fm][fn] = __builtin_amdgcn_mfma_f32_16x16x32_bf16(a_hi, b_hi, acc[fm][fn], 0, 0, 0);
        acc[fm][fn] = __builtin_amdgcn_mfma_f32_16x16x32_bf16(a_hi, b_lo, acc[fm][fn], 0, 0, 0);
        acc[fm][fn] = __builtin_amdgcn_mfma_f32_16x16x32_bf16(a_lo, b_hi, acc[fm][fn], 0, 0, 0);
      }
    }
  };

  wissue(wA, 0);
  for (int s = 0; s < ksteps; s += 2) {
    if (s + 1 < ksteps) wissue(wB, s + 1);      // W(s+1) flies under tile s
    do_tile(s, wA);
    if (s + 1 < ksteps) {
      if (s + 2 < ksteps) wissue(wA, s + 2);
      do_tile(s + 1, wB);
    }
  }

  // epilogue: D layout col=lane&15, row=(lane>>4)*4+reg  [m89-verified]
  float* pout = partials + (size_t)ks * 524288;
  const int rq = lane >> 4;
#pragma unroll
  for (int fm = 0; fm < 8; fm++)
#pragma unroll
    for (int fn = 0; fn < 2; fn++)
#pragma unroll
      for (int r = 0; r < 4; r++) {
        int row = fm * 16 + rq * 4 + r;
        int col = n0 + fn * 16 + lr;
        __builtin_nontemporal_store(acc[fm][fn][r], pout + (size_t)row * 4096 + col);
      }
}

// ---------------------------------------------------------------------------
// 4) reduce K-slices + bias + ReLU -> A2 in [kp4][128][4] layout, or fp32 x2
// ---------------------------------------------------------------------------
__global__ void reduce_k(const float* __restrict__ partials, const float* __restrict__ bias,
                         uint32_t* __restrict__ outhi, uint32_t* __restrict__ outlo,
                         float* __restrict__ fout, int KS) {
  int idx = blockIdx.x * 256 + threadIdx.x;
  int base = idx * 4;                               // 524288 total elems
  float4 s = make_float4(0.f, 0.f, 0.f, 0.f);
  for (int k = 0; k < KS; k++) {
    const float4 p = *(const float4*)(partials + (size_t)k * 524288 + base);
    s.x += p.x; s.y += p.y; s.z += p.z; s.w += p.w;
  }
  const float4 bv = *(const float4*)(bias + (base & 4095));
  s.x = fmaxf(s.x + bv.x, 0.f); s.y = fmaxf(s.y + bv.y, 0.f);
  s.z = fmaxf(s.z + bv.z, 0.f); s.w = fmaxf(s.w + bv.w, 0.f);
  if (outhi) {
    uint32_t h0, l0, h1, l1;
    pack_pair(s.x, s.y, h0, l0);
    pack_pair(s.z, s.w, h1, l1);
    int r = base >> 12, c = base & 4095, kp0 = c >> 1;   // kp0 even, kp0&3 in {0,2}
    size_t ad = ((size_t)(kp0 >> 2) * 128 + r) * 4 + (kp0 & 3);
    *(uint2*)(outhi + ad) = make_uint2(h0, h1);
    *(uint2*)(outlo + ad) = make_uint2(l0, l1);
  } else {
    *(float4*)(fout + base) = s;
  }
}

// ---------------------------------------------------------------------------
// 5) heads: logits = x2 @ [Ws|Wb] + [bs|bb]; softmax over first 21; concat
// ---------------------------------------------------------------------------
__global__ void heads_k(const float* __restrict__ x2, const float* __restrict__ Ws,
                        const float* __restrict__ bs, const float* __restrict__ Wb,
                        const float* __restrict__ bb, float* __restrict__ out) {
  int n = blockIdx.x, t = threadIdx.x;
  int j = t & 127, kq = t >> 7;    // kq 0..3
  float a0 = 0.f, a1 = 0.f, a2 = 0.f, a3 = 0.f;
  if (j < 105) {
    const float* xp = x2 + (size_t)n * 4096 + kq * 1024;
    const float* wq;
    int stride;
    if (j < 21) { wq = Ws + (size_t)kq * 1024 * 21 + j; stride = 21; }
    else        { wq = Wb + (size_t)kq * 1024 * 84 + (j - 21); stride = 84; }
    for (int k = 0; k < 1024; k += 4) {
      const float4 xv = *(const float4*)(xp + k);
      a0 += xv.x * wq[(size_t)k * stride];
      a1 += xv.y * wq[(size_t)(k + 1) * stride];
      a2 += xv.z * wq[(size_t)(k + 2) * stride];
      a3 += xv.w * wq[(size_t)(k + 3) * stride];
    }
  }
  __shared__ float sacc[512];
  __shared__ float slog[105];
  sacc[t] = (a0 + a1) + (a2 + a3);
  __syncthreads();
  if (t < 105)
    slog[t] = (sacc[t] + sacc[t + 128]) + (sacc[t + 256] + sacc[t + 384]) +
              (t < 21 ? bs[t] : bb[t - 21]);
  __syncthreads();
  if (t < 105) {
    float v = slog[t];
    if (t < 21) {
      float m = slog[0];
      for (int q = 1; q < 21; q++) m = fmaxf(m, slog[q]);
      float ssum = 0.f;
      for (int q = 0; q < 21; q++) ssum += expf(slog[q] - m);
      v = expf(v - m) / ssum;
    }
    out[(size_t)n * 105 + t] = v;
  }
}

// ---------------------------------------------------------------------------
extern "C" void kernel_launch(void* const* d_in, const int* in_sizes, int n_in,
                              void* d_out, int out_size, void* d_ws, size_t ws_size,
                              hipStream_t stream) {
  const float* feats = (const float*)d_in[0];
  const float* rois  = (const float*)d_in[1];
  const float* W6 = (const float*)d_in[2];
  const float* b6 = (const float*)d_in[3];
  const float* W7 = (const float*)d_in[4];
  const float* b7 = (const float*)d_in[5];
  const float* Wsp = (const float*)d_in[6];
  const float* bsp = (const float*)d_in[7];
  const float* Wbp = (const float*)d_in[8];
  const float* bbp = (const float*)d_in[9];
  float* out = (float*)d_out;

  char* ws = (char*)d_ws;
  size_t o = 0;
  float*    feats_t = (float*)(ws + o);    o += (size_t)512 * 1024 * 4;     // 2MB
  uint32_t* AhiT    = (uint32_t*)(ws + o); o += (size_t)128 * 12544 * 4;    // 6.4MB
  uint32_t* AloT    = (uint32_t*)(ws + o); o += (size_t)128 * 12544 * 4;    // 6.4MB
  uint32_t* A2hi    = (uint32_t*)(ws + o); o += (size_t)128 * 2048 * 4;     // 1MB
  uint32_t* A2lo    = (uint32_t*)(ws + o); o += (size_t)128 * 2048 * 4;     // 1MB
  float*    x2      = (float*)(ws + o);    o += (size_t)128 * 4096 * 4;     // 2MB
  size_t fixed = o;
  int KS = 16;
  while (KS > 1 && fixed + (size_t)KS * 524288 * 4 > ws_size) KS >>= 1;
  float* partials = (float*)(ws + o);
  int ksh = (KS == 16) ? 4 : (KS == 8) ? 3 : (KS == 4) ? 2 : (KS == 2) ? 1 : 0;

  hipLaunchKernelGGL(transpose_k, dim3(128), dim3(256), 0, stream, feats, feats_t);
  hipLaunchKernelGGL(pool_k, dim3(256), dim3(256), 0, stream, feats_t, rois, AhiT, AloT);
  hipLaunchKernelGGL(gemm_nb, dim3(32 << ksh), dim3(256), 0, stream,
                     AhiT, AloT, W6, partials, 25088 / (KS * 32), ksh);
  hipLaunchKernelGGL(reduce_k, dim3(512), dim3(256), 0, stream,
                     partials, b6, A2hi, A2lo, (float*)nullptr, KS);
  hipLaunchKernelGGL(gemm_nb, dim3(32 << ksh), dim3(256), 0, stream,
                     A2hi, A2lo, W7, partials, 4096 / (KS * 32), ksh);
  hipLaunchKernelGGL(reduce_k, dim3(512), dim3(256), 0, stream,
                     partials, b7, (uint32_t*)nullptr, (uint32_t*)nullptr, x2, KS);
  hipLaunchKernelGGL(heads_k, dim3(128), dim3(512), 0, stream,
                     x2, Wsp, bsp, Wbp, bbp, out);
}